// Round 1
// 1076.953 us; speedup vs baseline: 2.0892x; 2.0892x over previous
//
#include <hip/hip_runtime.h>

#define GAMMA 0.05f
#define LNEPS 1e-12f
#define HDIMT 768
#define SDIM  2048
#define NHEAD 12
#define HDHEAD 64
#define MTOT  4096
#define BHEADS 24
#define OUT0E ((size_t)MTOT * HDIMT)   // element offset of probs in d_out

typedef __attribute__((ext_vector_type(8))) short short8;
typedef __attribute__((ext_vector_type(4))) float f32x4;

#define MFMA16(a, b, c) __builtin_amdgcn_mfma_f32_16x16x32_bf16((a), (b), (c), 0, 0, 0)

__device__ __forceinline__ float bf2f(unsigned short u) {
    union { unsigned int i; float f; } c; c.i = ((unsigned int)u) << 16; return c.f;
}
__device__ __forceinline__ unsigned short f2bf(float f) {
    union { float f; unsigned int i; } c; c.f = f;
    unsigned int i = c.i;
    i += 0x7FFFu + ((i >> 16) & 1u);
    return (unsigned short)(i >> 16);
}
__device__ __forceinline__ void splitbf(float v, unsigned short& h, unsigned short& l) {
    h = f2bf(v);
    l = f2bf(v - bf2f(h));
}

__device__ __forceinline__ void load8f(const void* p, size_t idx, int isbf, float* r) {
    if (isbf) {
        const unsigned short* b = (const unsigned short*)p + idx;
        uint4 u = *(const uint4*)b;
        const unsigned short* pu = (const unsigned short*)&u;
        #pragma unroll
        for (int j = 0; j < 8; ++j) r[j] = bf2f(pu[j]);
    } else {
        const float* f = (const float*)p + idx;
        float4 a = *(const float4*)f, c = *(const float4*)(f + 4);
        r[0] = a.x; r[1] = a.y; r[2] = a.z; r[3] = a.w;
        r[4] = c.x; r[5] = c.y; r[6] = c.z; r[7] = c.w;
    }
}
__device__ __forceinline__ float load1f(const void* p, size_t idx, int isbf) {
    return isbf ? bf2f(((const unsigned short*)p)[idx]) : ((const float*)p)[idx];
}

__global__ void detect_kernel(const void* __restrict__ x, int* __restrict__ flag) {
    __shared__ int cnt;
    if (threadIdx.x == 0) cnt = 0;
    __syncthreads();
    const unsigned short* u = (const unsigned short*)x;
    unsigned short v = u[2 * threadIdx.x];
    int e = (v >> 7) & 0xFF;
    int ok = (e >= 100 && e <= 140) ? 1 : 0;
    atomicAdd(&cnt, ok);
    __syncthreads();
    if (threadIdx.x == 0) flag[0] = (cnt >= 192) ? 1 : 0;
}

// ---------------- QKV projection: fp32 VALU GEMM, bf16 hi/lo split outputs ---
// q,k -> [bh][s][64] (hi,lo);  v -> transposed [bh][d][s] (hi,lo)
__global__ __launch_bounds__(256) void qkv_kernel(
    const void* __restrict__ x,
    const void* __restrict__ Wq, const void* __restrict__ bq,
    const void* __restrict__ Wk, const void* __restrict__ bk,
    const void* __restrict__ Wv, const void* __restrict__ bv,
    unsigned short* __restrict__ qh, unsigned short* __restrict__ ql,
    unsigned short* __restrict__ kh, unsigned short* __restrict__ kl,
    unsigned short* __restrict__ vth, unsigned short* __restrict__ vtl,
    const int* __restrict__ flag)
{
    __shared__ float a_s[64][36];
    __shared__ float b_s[64][36];

    const int isbf = flag[0];
    const int tid = threadIdx.x;
    const int tx = tid & 15, ty = tid >> 4;
    const int m0 = blockIdx.x * 64;
    const int hh = blockIdx.y;
    const int n0 = hh * 64;
    const int z  = blockIdx.z;

    const void* W    = (z == 0) ? Wq : (z == 1) ? Wk : Wv;
    const void* bias = (z == 0) ? bq : (z == 1) ? bk : bv;

    const int lr = tid >> 2;
    const int lc = (tid & 3) * 8;

    float acc[4][4] = {};

    for (int k0 = 0; k0 < HDIMT; k0 += 32) {
        __syncthreads();
        {
            float av[8], bv8[8];
            load8f(x, (size_t)(m0 + lr) * HDIMT + k0 + lc, isbf, av);
            load8f(W, (size_t)(n0 + lr) * HDIMT + k0 + lc, isbf, bv8);
            #pragma unroll
            for (int j = 0; j < 8; ++j) a_s[lr][lc + j] = av[j];
            #pragma unroll
            for (int j = 0; j < 8; ++j) b_s[lr][lc + j] = bv8[j];
        }
        __syncthreads();
        #pragma unroll
        for (int kk = 0; kk < 32; kk += 4) {
            float4 a4[4], b4[4];
            #pragma unroll
            for (int i = 0; i < 4; ++i) a4[i] = *(const float4*)&a_s[ty * 4 + i][kk];
            #pragma unroll
            for (int j = 0; j < 4; ++j) b4[j] = *(const float4*)&b_s[tx * 4 + j][kk];
            #pragma unroll
            for (int i = 0; i < 4; ++i)
                #pragma unroll
                for (int j = 0; j < 4; ++j)
                    acc[i][j] += a4[i].x * b4[j].x + a4[i].y * b4[j].y +
                                 a4[i].z * b4[j].z + a4[i].w * b4[j].w;
        }
    }

    float bb[4];
    #pragma unroll
    for (int j = 0; j < 4; ++j) bb[j] = load1f(bias, n0 + tx * 4 + j, isbf);

    if (z < 2) {
        unsigned short* oh = z ? kh : qh;
        unsigned short* ol = z ? kl : ql;
        #pragma unroll
        for (int i = 0; i < 4; ++i) {
            const int m = m0 + ty * 4 + i;
            const int b = m >> 11, s = m & 2047;
            ushort4 hv, lv;
            { float v = acc[i][0] + bb[0]; splitbf(v, hv.x, lv.x); }
            { float v = acc[i][1] + bb[1]; splitbf(v, hv.y, lv.y); }
            { float v = acc[i][2] + bb[2]; splitbf(v, hv.z, lv.z); }
            { float v = acc[i][3] + bb[3]; splitbf(v, hv.w, lv.w); }
            const size_t base = ((size_t)(b * NHEAD + hh) * SDIM + s) * HDHEAD + tx * 4;
            *(ushort4*)(oh + base) = hv;
            *(ushort4*)(ol + base) = lv;
        }
    } else {
        const int b = m0 >> 11, s0 = (m0 & 2047) + ty * 4;
        #pragma unroll
        for (int j = 0; j < 4; ++j) {
            const int d = tx * 4 + j;
            ushort4 hv, lv;
            { float v = acc[0][j] + bb[j]; splitbf(v, hv.x, lv.x); }
            { float v = acc[1][j] + bb[j]; splitbf(v, hv.y, lv.y); }
            { float v = acc[2][j] + bb[j]; splitbf(v, hv.z, lv.z); }
            { float v = acc[3][j] + bb[j]; splitbf(v, hv.w, lv.w); }
            const size_t base = ((size_t)(b * NHEAD + hh) * HDHEAD + d) * SDIM + s0;
            *(ushort4*)(vth + base) = hv;
            *(ushort4*)(vtl + base) = lv;
        }
    }
}

// ---------------- Attention: split-bf16 MFMA, XOR-swizzled LDS ---------------
// Stage a 64x64 bf16 tile (hi+lo) into swizzled LDS. 512 x 16B slots.
#define STAGE64(dsth, dstl, srch, srcl, SROW)                                     \
    {                                                                             \
        _Pragma("unroll")                                                         \
        for (int p_ = 0; p_ < 2; ++p_) {                                          \
            const int idx_ = tid + p_ * 256;                                      \
            const int row_ = idx_ >> 3, slot_ = idx_ & 7;                         \
            const int off_ = (row_ << 7) + ((slot_ << 4) ^ ((row_ & 7) << 4));    \
            *(uint4*)((char*)(dsth) + off_) =                                     \
                *(const uint4*)((srch) + (size_t)row_ * (SROW) + slot_ * 8);      \
            *(uint4*)((char*)(dstl) + off_) =                                     \
                *(const uint4*)((srcl) + (size_t)row_ * (SROW) + slot_ * 8);      \
        }                                                                         \
    }

#define FRAG(buf, row, kb)                                                        \
    (*(const short8*)((const char*)(buf) +                                        \
                      (((row) << 7) + ((kb) ^ (((row) & 7) << 4)))))

__global__ __launch_bounds__(256) void attn_kernel(
    const unsigned short* __restrict__ qh, const unsigned short* __restrict__ ql,
    const unsigned short* __restrict__ kh, const unsigned short* __restrict__ kl,
    const unsigned short* __restrict__ vth, const unsigned short* __restrict__ vtl,
    float* __restrict__ ctx, void* __restrict__ dout,
    const int* __restrict__ flag)
{
    __shared__ alignas(16) unsigned short Qh[4096], Ql[4096];
    __shared__ alignas(16) unsigned short Kh[4096], Kl[4096];   // doubles as P (hi/lo)
    __shared__ alignas(16) unsigned short Vh[4096], Vl[4096];
    __shared__ float linv[64];

    const int isbf = flag[0];
    const int tid  = threadIdx.x;
    const int lane = tid & 63;
    const int w    = tid >> 6;           // wave 0..3 -> q rows [w*16, w*16+16)
    const int l15  = lane & 15, g = lane >> 4;
    const int bh   = blockIdx.y;
    const int r0   = blockIdx.x * 64;

    // ---- stage Q strip (persistent) ----
    {
        const unsigned short* sh = qh + ((size_t)bh * SDIM + r0) * HDHEAD;
        const unsigned short* sl = ql + ((size_t)bh * SDIM + r0) * HDHEAD;
        STAGE64(Qh, Ql, sh, sl, HDHEAD);
    }
    __syncthreads();

    short8 aqh[2], aql[2];
    #pragma unroll
    for (int ks = 0; ks < 2; ++ks) {
        const int row = w * 16 + l15;
        const int kb  = (g << 4) + (ks << 6);
        aqh[ks] = FRAG(Qh, row, kb);
        aql[ks] = FRAG(Ql, row, kb);
    }

    const f32x4 fzero = {0.0f, 0.0f, 0.0f, 0.0f};

    // ================= pass 1: row sums of exp(scores) (no max needed:
    // |scores| <~ 15, exp fits fp32; identical to softmax) =================
    float lsum[4] = {0.0f, 0.0f, 0.0f, 0.0f};

    for (int kt = 0; kt < 32; ++kt) {
        __syncthreads();
        {
            const unsigned short* sh = kh + ((size_t)bh * SDIM + kt * 64) * HDHEAD;
            const unsigned short* sl = kl + ((size_t)bh * SDIM + kt * 64) * HDHEAD;
            STAGE64(Kh, Kl, sh, sl, HDHEAD);
        }
        __syncthreads();

        f32x4 acc[4];
        #pragma unroll
        for (int c = 0; c < 4; ++c) acc[c] = fzero;

        #pragma unroll
        for (int c = 0; c < 4; ++c) {
            #pragma unroll
            for (int ks = 0; ks < 2; ++ks) {
                const int row = c * 16 + l15;
                const int kb  = (g << 4) + (ks << 6);
                short8 bh8 = FRAG(Kh, row, kb);
                short8 bl8 = FRAG(Kl, row, kb);
                acc[c] = MFMA16(aqh[ks], bh8, acc[c]);
                acc[c] = MFMA16(aql[ks], bh8, acc[c]);
                acc[c] = MFMA16(aqh[ks], bl8, acc[c]);
            }
        }
        #pragma unroll
        for (int c = 0; c < 4; ++c) {
            #pragma unroll
            for (int r = 0; r < 4; ++r) lsum[r] += __expf(acc[c][r]);
        }
    }

    #pragma unroll
    for (int d = 1; d < 16; d <<= 1) {
        #pragma unroll
        for (int r = 0; r < 4; ++r) lsum[r] += __shfl_xor(lsum[r], d, 64);
    }
    #pragma unroll
    for (int r = 0; r < 4; ++r)
        if (l15 == r) linv[w * 16 + g * 4 + r] = 1.0f / lsum[r];
    __syncthreads();

    float inv[4];
    #pragma unroll
    for (int r = 0; r < 4; ++r) inv[r] = linv[w * 16 + g * 4 + r];

    // ================= pass 2: recompute scores (bitwise-identical),
    // write probs, PV accumulate =================
    f32x4 cacc[4];
    #pragma unroll
    for (int c = 0; c < 4; ++c) cacc[c] = fzero;

    for (int kt = 0; kt < 32; ++kt) {
        __syncthreads();   // prior-iter PV reads done
        {
            const unsigned short* sh = kh + ((size_t)bh * SDIM + kt * 64) * HDHEAD;
            const unsigned short* sl = kl + ((size_t)bh * SDIM + kt * 64) * HDHEAD;
            STAGE64(Kh, Kl, sh, sl, HDHEAD);
            const unsigned short* vh = vth + (size_t)bh * HDHEAD * SDIM + (size_t)(kt * 64);
            const unsigned short* vl = vtl + (size_t)bh * HDHEAD * SDIM + (size_t)(kt * 64);
            STAGE64(Vh, Vl, vh, vl, SDIM);
        }
        __syncthreads();

        f32x4 acc[4];
        #pragma unroll
        for (int c = 0; c < 4; ++c) acc[c] = fzero;

        #pragma unroll
        for (int c = 0; c < 4; ++c) {
            #pragma unroll
            for (int ks = 0; ks < 2; ++ks) {
                const int row = c * 16 + l15;
                const int kb  = (g << 4) + (ks << 6);
                short8 bh8 = FRAG(Kh, row, kb);
                short8 bl8 = FRAG(Kl, row, kb);
                acc[c] = MFMA16(aqh[ks], bh8, acc[c]);
                acc[c] = MFMA16(aql[ks], bh8, acc[c]);
                acc[c] = MFMA16(aqh[ks], bl8, acc[c]);
            }
        }
        __syncthreads();   // all waves done reading K; K buffer becomes P

        #pragma unroll
        for (int c = 0; c < 4; ++c) {
            const int t = c * 16 + l15;
            #pragma unroll
            for (int r = 0; r < 4; ++r) {
                const int q = w * 16 + g * 4 + r;
                const float p = __expf(acc[c][r]) * inv[r];
                const size_t go = OUT0E + ((size_t)bh * SDIM + (r0 + q)) * SDIM
                                + (size_t)(kt * 64 + t);
                if (isbf) ((unsigned short*)dout)[go] = f2bf(p);
                else      ((float*)dout)[go] = p;
                unsigned short ph_, pl_;
                splitbf(p, ph_, pl_);
                const int off = (q << 7) + ((t << 1) ^ ((q & 7) << 4));
                *(unsigned short*)((char*)Kh + off) = ph_;
                *(unsigned short*)((char*)Kl + off) = pl_;
            }
        }
        __syncthreads();   // P visible to all lanes

        short8 pah[2], pal[2];
        #pragma unroll
        for (int ks = 0; ks < 2; ++ks) {
            const int row = w * 16 + l15;
            const int kb  = (g << 4) + (ks << 6);
            pah[ks] = FRAG(Kh, row, kb);
            pal[ks] = FRAG(Kl, row, kb);
        }
        #pragma unroll
        for (int dsb = 0; dsb < 4; ++dsb) {
            #pragma unroll
            for (int ks = 0; ks < 2; ++ks) {
                const int row = dsb * 16 + l15;
                const int kb  = (g << 4) + (ks << 6);
                short8 vh8 = FRAG(Vh, row, kb);
                short8 vl8 = FRAG(Vl, row, kb);
                cacc[dsb] = MFMA16(pah[ks], vh8, cacc[dsb]);
                cacc[dsb] = MFMA16(pal[ks], vh8, cacc[dsb]);
                cacc[dsb] = MFMA16(pah[ks], vl8, cacc[dsb]);
            }
        }
    }

    const int bb_ = bh / NHEAD, hh_ = bh % NHEAD;
    #pragma unroll
    for (int dsb = 0; dsb < 4; ++dsb) {
        #pragma unroll
        for (int r = 0; r < 4; ++r) {
            const int q = w * 16 + g * 4 + r;
            const int d = dsb * 16 + l15;
            ctx[((size_t)(bb_ * SDIM + r0 + q)) * HDIMT + hh_ * HDHEAD + d] = cacc[dsb][r];
        }
    }
}

__global__ __launch_bounds__(256) void oproj_kernel(
    const float* __restrict__ ctx,
    const void* __restrict__ Wo, const void* __restrict__ bo,
    const void* __restrict__ x, float* __restrict__ y,
    const int* __restrict__ flag)
{
    __shared__ float a_s[64][36];
    __shared__ float b_s[64][36];

    const int isbf = flag[0];
    const int tid = threadIdx.x;
    const int tx = tid & 15, ty = tid >> 4;
    const int m0 = blockIdx.x * 64, n0 = blockIdx.y * 64;
    const int lr = tid >> 2, lc = (tid & 3) * 8;

    float acc[4][4] = {};

    for (int k0 = 0; k0 < HDIMT; k0 += 32) {
        __syncthreads();
        {
            const float* ap = ctx + (size_t)(m0 + lr) * HDIMT + k0 + lc;
            *(float4*)&a_s[lr][lc]     = *(const float4*)ap;
            *(float4*)&a_s[lr][lc + 4] = *(const float4*)(ap + 4);

            float wv[8];
            load8f(Wo, (size_t)(n0 + lr) * HDIMT + k0 + lc, isbf, wv);
            #pragma unroll
            for (int j = 0; j < 8; ++j)
                b_s[lr][lc + j] = wv[j] + GAMMA * fmaxf(wv[j], 0.0f);
        }
        __syncthreads();
        #pragma unroll
        for (int kk = 0; kk < 32; kk += 4) {
            float4 a4[4], b4[4];
            #pragma unroll
            for (int i = 0; i < 4; ++i) a4[i] = *(const float4*)&a_s[ty * 4 + i][kk];
            #pragma unroll
            for (int j = 0; j < 4; ++j) b4[j] = *(const float4*)&b_s[tx * 4 + j][kk];
            #pragma unroll
            for (int i = 0; i < 4; ++i)
                #pragma unroll
                for (int j = 0; j < 4; ++j)
                    acc[i][j] += a4[i].x * b4[j].x + a4[i].y * b4[j].y +
                                 a4[i].z * b4[j].z + a4[i].w * b4[j].w;
        }
    }

    float pb[4];
    #pragma unroll
    for (int j = 0; j < 4; ++j) {
        float bb = load1f(bo, n0 + tx * 4 + j, isbf);
        pb[j] = bb + GAMMA * fmaxf(bb, 0.0f);
    }

    #pragma unroll
    for (int i = 0; i < 4; ++i) {
        const int m = m0 + ty * 4 + i;
        const size_t xb = (size_t)m * HDIMT + n0 + tx * 4;
        float4 o;
        o.x = acc[i][0] + pb[0] + load1f(x, xb + 0, isbf);
        o.y = acc[i][1] + pb[1] + load1f(x, xb + 1, isbf);
        o.z = acc[i][2] + pb[2] + load1f(x, xb + 2, isbf);
        o.w = acc[i][3] + pb[3] + load1f(x, xb + 3, isbf);
        *(float4*)(y + (size_t)m * HDIMT + n0 + tx * 4) = o;
    }
}

__global__ __launch_bounds__(256) void ln_kernel(
    const float* __restrict__ y, void* __restrict__ out,
    const int* __restrict__ flag)
{
    __shared__ float red[256];
    const int isbf = flag[0];
    const int m = blockIdx.x;
    const int tid = threadIdx.x;
    const float* yr = y + (size_t)m * HDIMT;

    float v0 = yr[tid], v1 = yr[tid + 256], v2 = yr[tid + 512];

    red[tid] = v0 + v1 + v2;
    __syncthreads();
    for (int s = 128; s > 0; s >>= 1) {
        if (tid < s) red[tid] += red[tid + s];
        __syncthreads();
    }
    const float mean = red[0] * (1.0f / 768.0f);
    __syncthreads();

    const float d0 = v0 - mean, d1 = v1 - mean, d2 = v2 - mean;
    red[tid] = d0 * d0 + d1 * d1 + d2 * d2;
    __syncthreads();
    for (int s = 128; s > 0; s >>= 1) {
        if (tid < s) red[tid] += red[tid + s];
        __syncthreads();
    }
    const float var = red[0] * (1.0f / 767.0f);   // ddof=1
    const float inv = 1.0f / (sqrtf(var) + LNEPS);

    const size_t base = (size_t)m * HDIMT;
    if (isbf) {
        unsigned short* o = (unsigned short*)out;
        o[base + tid]       = f2bf(d0 * inv);
        o[base + tid + 256] = f2bf(d1 * inv);
        o[base + tid + 512] = f2bf(d2 * inv);
    } else {
        float* o = (float*)out;
        o[base + tid]       = d0 * inv;
        o[base + tid + 256] = d1 * inv;
        o[base + tid + 512] = d2 * inv;
    }
}

extern "C" void kernel_launch(void* const* d_in, const int* in_sizes, int n_in,
                              void* d_out, int out_size, void* d_ws, size_t ws_size,
                              hipStream_t stream)
{
    (void)in_sizes; (void)n_in; (void)out_size; (void)ws_size;

    const void* x  = d_in[0];
    const void* Wq = d_in[1];
    const void* bq = d_in[2];
    const void* Wk = d_in[3];
    const void* bk = d_in[4];
    const void* Wv = d_in[5];
    const void* bv = d_in[6];
    const void* Wo = d_in[7];
    const void* bo = d_in[8];

    const size_t NE = (size_t)BHEADS * SDIM * HDHEAD;  // 3,145,728 elements per array
    unsigned short* qh  = (unsigned short*)d_ws;
    unsigned short* ql  = qh  + NE;
    unsigned short* kh  = ql  + NE;
    unsigned short* kl  = kh  + NE;
    unsigned short* vth = kl  + NE;
    unsigned short* vtl = vth + NE;
    float* ctx = (float*)(vtl + NE);          // 12.58 MB
    float* y   = (float*)d_ws;                // aliases q/k bf16 arrays (dead after attn)
    int* flag  = (int*)(ctx + OUT0E);         // byte offset 50,331,648 (same footprint as before)

    detect_kernel<<<1, 256, 0, stream>>>(x, flag);
    qkv_kernel<<<dim3(64, 12, 3), 256, 0, stream>>>(x, Wq, bq, Wk, bk, Wv, bv,
                                                    qh, ql, kh, kl, vth, vtl, flag);
    attn_kernel<<<dim3(32, 24), 256, 0, stream>>>(qh, ql, kh, kl, vth, vtl, ctx, d_out, flag);
    oproj_kernel<<<dim3(64, 12), 256, 0, stream>>>(ctx, Wo, bo, x, y, flag);
    ln_kernel<<<MTOT, 256, 0, stream>>>(y, d_out, flag);
}

// Round 2
// 700.932 us; speedup vs baseline: 3.2100x; 1.5365x over previous
//
#include <hip/hip_runtime.h>

#define GAMMA 0.05f
#define LNEPS 1e-12f
#define HDIMT 768
#define SDIM  2048
#define NHEAD 12
#define HDHEAD 64
#define MTOT  4096
#define BHEADS 24
#define OUT0E ((size_t)MTOT * HDIMT)   // element offset of probs in d_out
#define NXEL  ((size_t)MTOT * HDIMT)   // x elements: 3,145,728
#define WNEL  ((size_t)HDIMT * HDIMT)  // W elements: 589,824
#define NEATT ((size_t)BHEADS * SDIM * HDHEAD)  // per q/k/v array: 3,145,728

typedef __attribute__((ext_vector_type(8))) short short8;
typedef __attribute__((ext_vector_type(4))) float f32x4;

#define MFMA16(a, b, c) __builtin_amdgcn_mfma_f32_16x16x32_bf16((a), (b), (c), 0, 0, 0)

__device__ __forceinline__ float bf2f(unsigned short u) {
    union { unsigned int i; float f; } c; c.i = ((unsigned int)u) << 16; return c.f;
}
__device__ __forceinline__ unsigned short f2bf(float f) {
    union { float f; unsigned int i; } c; c.f = f;
    unsigned int i = c.i;
    i += 0x7FFFu + ((i >> 16) & 1u);
    return (unsigned short)(i >> 16);
}
__device__ __forceinline__ void splitbf(float v, unsigned short& h, unsigned short& l) {
    h = f2bf(v);
    l = f2bf(v - bf2f(h));
}

__device__ __forceinline__ void load8f(const void* p, size_t idx, int isbf, float* r) {
    if (isbf) {
        const unsigned short* b = (const unsigned short*)p + idx;
        uint4 u = *(const uint4*)b;
        const unsigned short* pu = (const unsigned short*)&u;
        #pragma unroll
        for (int j = 0; j < 8; ++j) r[j] = bf2f(pu[j]);
    } else {
        const float* f = (const float*)p + idx;
        float4 a = *(const float4*)f, c = *(const float4*)(f + 4);
        r[0] = a.x; r[1] = a.y; r[2] = a.z; r[3] = a.w;
        r[4] = c.x; r[5] = c.y; r[6] = c.z; r[7] = c.w;
    }
}
__device__ __forceinline__ float load1f(const void* p, size_t idx, int isbf) {
    return isbf ? bf2f(((const unsigned short*)p)[idx]) : ((const float*)p)[idx];
}

__global__ void detect_kernel(const void* __restrict__ x, int* __restrict__ flag) {
    __shared__ int cnt;
    if (threadIdx.x == 0) cnt = 0;
    __syncthreads();
    const unsigned short* u = (const unsigned short*)x;
    unsigned short v = u[2 * threadIdx.x];
    int e = (v >> 7) & 0xFF;
    int ok = (e >= 100 && e <= 140) ? 1 : 0;
    atomicAdd(&cnt, ok);
    __syncthreads();
    if (threadIdx.x == 0) flag[0] = (cnt >= 192) ? 1 : 0;
}

// ---------------- prep: split x and W into bf16 hi/lo (gamma folded into Wo) --
__global__ __launch_bounds__(256) void prep_kernel(
    const void* __restrict__ x,
    const void* __restrict__ Wq, const void* __restrict__ Wk,
    const void* __restrict__ Wv, const void* __restrict__ Wo,
    unsigned short* __restrict__ xh, unsigned short* __restrict__ xl,
    unsigned short* __restrict__ wqh, unsigned short* __restrict__ wql,
    unsigned short* __restrict__ wkh, unsigned short* __restrict__ wkl,
    unsigned short* __restrict__ wvh, unsigned short* __restrict__ wvl,
    unsigned short* __restrict__ woh, unsigned short* __restrict__ wol,
    const int* __restrict__ flag)
{
    const int isbf = flag[0];
    const int z = blockIdx.y;
    const size_t i8 = ((size_t)blockIdx.x * 256 + threadIdx.x) * 8;
    const void* src; unsigned short* dh; unsigned short* dl;
    size_t n; int gam = 0;
    if (z == 0)      { src = x;  dh = xh;  dl = xl;  n = NXEL; }
    else if (z == 1) { src = Wq; dh = wqh; dl = wql; n = WNEL; }
    else if (z == 2) { src = Wk; dh = wkh; dl = wkl; n = WNEL; }
    else if (z == 3) { src = Wv; dh = wvh; dl = wvl; n = WNEL; }
    else             { src = Wo; dh = woh; dl = wol; n = WNEL; gam = 1; }
    if (i8 >= n) return;

    float v[8]; load8f(src, i8, isbf, v);
    alignas(16) unsigned short hv[8], lv[8];
    #pragma unroll
    for (int j = 0; j < 8; ++j) {
        float f = v[j];
        if (gam) f += GAMMA * fmaxf(f, 0.0f);
        splitbf(f, hv[j], lv[j]);
    }
    *(uint4*)(dh + i8) = *(const uint4*)hv;
    *(uint4*)(dl + i8) = *(const uint4*)lv;
}

// XOR-swizzled LDS fragment read (same scheme as verified attn kernel)
#define FRAG(buf, row, kb)                                                        \
    (*(const short8*)((const char*)(buf) +                                        \
                      (((row) << 7) + ((kb) ^ (((row) & 7) << 4)))))

// ---------------- QKV projection: split-bf16 MFMA GEMM (128x64 tile) ---------
__global__ __launch_bounds__(256) void qkv_mfma(
    const unsigned short* __restrict__ xh, const unsigned short* __restrict__ xl,
    const unsigned short* __restrict__ wqh, const unsigned short* __restrict__ wql,
    const unsigned short* __restrict__ wkh, const unsigned short* __restrict__ wkl,
    const unsigned short* __restrict__ wvh, const unsigned short* __restrict__ wvl,
    const void* __restrict__ bq, const void* __restrict__ bk, const void* __restrict__ bv,
    unsigned short* __restrict__ qh, unsigned short* __restrict__ ql,
    unsigned short* __restrict__ kh, unsigned short* __restrict__ kl,
    unsigned short* __restrict__ vth, unsigned short* __restrict__ vtl,
    const int* __restrict__ flag)
{
    __shared__ alignas(16) unsigned short Ah[8192], Al[8192];
    __shared__ alignas(16) unsigned short Bh[4096], Bl[4096];

    const int isbf = flag[0];
    const int tid = threadIdx.x;
    const int lane = tid & 63, w = tid >> 6;
    const int l15 = lane & 15, g = lane >> 4;
    const int m0 = blockIdx.x * 128;
    const int h  = blockIdx.y;
    const int z  = blockIdx.z;

    const unsigned short* Wh = (z == 0) ? wqh : (z == 1) ? wkh : wvh;
    const unsigned short* Wl = (z == 0) ? wql : (z == 1) ? wkl : wvl;
    const void* bias = (z == 0) ? bq : (z == 1) ? bk : bv;

    f32x4 acc[2][4];
    #pragma unroll
    for (int i = 0; i < 2; ++i)
        #pragma unroll
        for (int c = 0; c < 4; ++c) acc[i][c] = (f32x4){0.0f, 0.0f, 0.0f, 0.0f};

    for (int k0 = 0; k0 < HDIMT; k0 += 64) {
        __syncthreads();
        #pragma unroll
        for (int p = 0; p < 4; ++p) {
            const int idx = tid + p * 256;
            const int row = idx >> 3, slot = idx & 7;
            const int off = (row << 7) + ((slot << 4) ^ ((row & 7) << 4));
            const size_t s = (size_t)(m0 + row) * HDIMT + k0 + slot * 8;
            *(uint4*)((char*)Ah + off) = *(const uint4*)(xh + s);
            *(uint4*)((char*)Al + off) = *(const uint4*)(xl + s);
        }
        #pragma unroll
        for (int p = 0; p < 2; ++p) {
            const int idx = tid + p * 256;
            const int row = idx >> 3, slot = idx & 7;
            const int off = (row << 7) + ((slot << 4) ^ ((row & 7) << 4));
            const size_t s = (size_t)(h * 64 + row) * HDIMT + k0 + slot * 8;
            *(uint4*)((char*)Bh + off) = *(const uint4*)(Wh + s);
            *(uint4*)((char*)Bl + off) = *(const uint4*)(Wl + s);
        }
        __syncthreads();

        #pragma unroll
        for (int ks = 0; ks < 2; ++ks) {
            const int kb = (g << 4) + (ks << 6);
            short8 a8h[2], a8l[2], b8h[4], b8l[4];
            #pragma unroll
            for (int i = 0; i < 2; ++i) {
                const int row = w * 32 + i * 16 + l15;
                a8h[i] = FRAG(Ah, row, kb);
                a8l[i] = FRAG(Al, row, kb);
            }
            #pragma unroll
            for (int c = 0; c < 4; ++c) {
                const int row = c * 16 + l15;
                b8h[c] = FRAG(Bh, row, kb);
                b8l[c] = FRAG(Bl, row, kb);
            }
            #pragma unroll
            for (int i = 0; i < 2; ++i)
                #pragma unroll
                for (int c = 0; c < 4; ++c) {
                    acc[i][c] = MFMA16(a8h[i], b8h[c], acc[i][c]);
                    acc[i][c] = MFMA16(a8l[i], b8h[c], acc[i][c]);
                    acc[i][c] = MFMA16(a8h[i], b8l[c], acc[i][c]);
                }
        }
    }

    float bb[4];
    #pragma unroll
    for (int c = 0; c < 4; ++c) bb[c] = load1f(bias, h * 64 + c * 16 + l15, isbf);

    if (z < 2) {
        unsigned short* oh = z ? kh : qh;
        unsigned short* ol = z ? kl : ql;
        #pragma unroll
        for (int i = 0; i < 2; ++i)
            #pragma unroll
            for (int c = 0; c < 4; ++c)
                #pragma unroll
                for (int r = 0; r < 4; ++r) {
                    const int m = m0 + w * 32 + i * 16 + g * 4 + r;
                    const int b = m >> 11, s = m & 2047;
                    const int d = c * 16 + l15;
                    unsigned short hu, lu;
                    splitbf(acc[i][c][r] + bb[c], hu, lu);
                    const size_t o = ((size_t)(b * NHEAD + h) * SDIM + s) * HDHEAD + d;
                    oh[o] = hu; ol[o] = lu;
                }
    } else {
        #pragma unroll
        for (int i = 0; i < 2; ++i)
            #pragma unroll
            for (int c = 0; c < 4; ++c) {
                const int m00 = m0 + w * 32 + i * 16 + g * 4;
                const int b = m00 >> 11, s0 = m00 & 2047;
                const int d = c * 16 + l15;
                ushort4 hv, lv;
                unsigned short* hp = (unsigned short*)&hv;
                unsigned short* lp = (unsigned short*)&lv;
                #pragma unroll
                for (int r = 0; r < 4; ++r)
                    splitbf(acc[i][c][r] + bb[c], hp[r], lp[r]);
                const size_t o = ((size_t)(b * NHEAD + h) * HDHEAD + d) * SDIM + s0;
                *(ushort4*)(vth + o) = hv;
                *(ushort4*)(vtl + o) = lv;
            }
    }
}

// ---------------- Attention: split-bf16 MFMA, XOR-swizzled LDS ---------------
#define STAGE64(dsth, dstl, srch, srcl, SROW)                                     \
    {                                                                             \
        _Pragma("unroll")                                                         \
        for (int p_ = 0; p_ < 2; ++p_) {                                          \
            const int idx_ = tid + p_ * 256;                                      \
            const int row_ = idx_ >> 3, slot_ = idx_ & 7;                         \
            const int off_ = (row_ << 7) + ((slot_ << 4) ^ ((row_ & 7) << 4));    \
            *(uint4*)((char*)(dsth) + off_) =                                     \
                *(const uint4*)((srch) + (size_t)row_ * (SROW) + slot_ * 8);      \
            *(uint4*)((char*)(dstl) + off_) =                                     \
                *(const uint4*)((srcl) + (size_t)row_ * (SROW) + slot_ * 8);      \
        }                                                                         \
    }

__global__ __launch_bounds__(256) void attn_kernel(
    const unsigned short* __restrict__ qh, const unsigned short* __restrict__ ql,
    const unsigned short* __restrict__ kh, const unsigned short* __restrict__ kl,
    const unsigned short* __restrict__ vth, const unsigned short* __restrict__ vtl,
    unsigned short* __restrict__ ctxh, unsigned short* __restrict__ ctxl,
    void* __restrict__ dout,
    const int* __restrict__ flag)
{
    __shared__ alignas(16) unsigned short Qh[4096], Ql[4096];
    __shared__ alignas(16) unsigned short Kh[4096], Kl[4096];   // doubles as P (hi/lo)
    __shared__ alignas(16) unsigned short Vh[4096], Vl[4096];
    __shared__ float linv[64];

    const int isbf = flag[0];
    const int tid  = threadIdx.x;
    const int lane = tid & 63;
    const int w    = tid >> 6;           // wave 0..3 -> q rows [w*16, w*16+16)
    const int l15  = lane & 15, g = lane >> 4;
    const int bh   = blockIdx.y;
    const int r0   = blockIdx.x * 64;

    {
        const unsigned short* sh = qh + ((size_t)bh * SDIM + r0) * HDHEAD;
        const unsigned short* sl = ql + ((size_t)bh * SDIM + r0) * HDHEAD;
        STAGE64(Qh, Ql, sh, sl, HDHEAD);
    }
    __syncthreads();

    short8 aqh[2], aql[2];
    #pragma unroll
    for (int ks = 0; ks < 2; ++ks) {
        const int row = w * 16 + l15;
        const int kb  = (g << 4) + (ks << 6);
        aqh[ks] = FRAG(Qh, row, kb);
        aql[ks] = FRAG(Ql, row, kb);
    }

    const f32x4 fzero = {0.0f, 0.0f, 0.0f, 0.0f};

    // ===== pass 1: row sums of exp(scores) =====
    float lsum[4] = {0.0f, 0.0f, 0.0f, 0.0f};

    for (int kt = 0; kt < 32; ++kt) {
        __syncthreads();
        {
            const unsigned short* sh = kh + ((size_t)bh * SDIM + kt * 64) * HDHEAD;
            const unsigned short* sl = kl + ((size_t)bh * SDIM + kt * 64) * HDHEAD;
            STAGE64(Kh, Kl, sh, sl, HDHEAD);
        }
        __syncthreads();

        f32x4 acc[4];
        #pragma unroll
        for (int c = 0; c < 4; ++c) acc[c] = fzero;

        #pragma unroll
        for (int c = 0; c < 4; ++c) {
            #pragma unroll
            for (int ks = 0; ks < 2; ++ks) {
                const int row = c * 16 + l15;
                const int kb  = (g << 4) + (ks << 6);
                short8 bh8 = FRAG(Kh, row, kb);
                short8 bl8 = FRAG(Kl, row, kb);
                acc[c] = MFMA16(aqh[ks], bh8, acc[c]);
                acc[c] = MFMA16(aql[ks], bh8, acc[c]);
                acc[c] = MFMA16(aqh[ks], bl8, acc[c]);
            }
        }
        #pragma unroll
        for (int c = 0; c < 4; ++c) {
            #pragma unroll
            for (int r = 0; r < 4; ++r) lsum[r] += __expf(acc[c][r]);
        }
    }

    #pragma unroll
    for (int d = 1; d < 16; d <<= 1) {
        #pragma unroll
        for (int r = 0; r < 4; ++r) lsum[r] += __shfl_xor(lsum[r], d, 64);
    }
    #pragma unroll
    for (int r = 0; r < 4; ++r)
        if (l15 == r) linv[w * 16 + g * 4 + r] = 1.0f / lsum[r];
    __syncthreads();

    float inv[4];
    #pragma unroll
    for (int r = 0; r < 4; ++r) inv[r] = linv[w * 16 + g * 4 + r];

    // ===== pass 2: recompute scores, write probs, PV accumulate =====
    f32x4 cacc[4];
    #pragma unroll
    for (int c = 0; c < 4; ++c) cacc[c] = fzero;

    for (int kt = 0; kt < 32; ++kt) {
        __syncthreads();
        {
            const unsigned short* sh = kh + ((size_t)bh * SDIM + kt * 64) * HDHEAD;
            const unsigned short* sl = kl + ((size_t)bh * SDIM + kt * 64) * HDHEAD;
            STAGE64(Kh, Kl, sh, sl, HDHEAD);
            const unsigned short* vh = vth + (size_t)bh * HDHEAD * SDIM + (size_t)(kt * 64);
            const unsigned short* vl = vtl + (size_t)bh * HDHEAD * SDIM + (size_t)(kt * 64);
            STAGE64(Vh, Vl, vh, vl, SDIM);
        }
        __syncthreads();

        f32x4 acc[4];
        #pragma unroll
        for (int c = 0; c < 4; ++c) acc[c] = fzero;

        #pragma unroll
        for (int c = 0; c < 4; ++c) {
            #pragma unroll
            for (int ks = 0; ks < 2; ++ks) {
                const int row = c * 16 + l15;
                const int kb  = (g << 4) + (ks << 6);
                short8 bh8 = FRAG(Kh, row, kb);
                short8 bl8 = FRAG(Kl, row, kb);
                acc[c] = MFMA16(aqh[ks], bh8, acc[c]);
                acc[c] = MFMA16(aql[ks], bh8, acc[c]);
                acc[c] = MFMA16(aqh[ks], bl8, acc[c]);
            }
        }
        __syncthreads();   // all waves done reading K; K buffer becomes P

        #pragma unroll
        for (int c = 0; c < 4; ++c) {
            const int t = c * 16 + l15;
            #pragma unroll
            for (int r = 0; r < 4; ++r) {
                const int q = w * 16 + g * 4 + r;
                const float p = __expf(acc[c][r]) * inv[r];
                const size_t go = OUT0E + ((size_t)bh * SDIM + (r0 + q)) * SDIM
                                + (size_t)(kt * 64 + t);
                if (isbf) ((unsigned short*)dout)[go] = f2bf(p);
                else      ((float*)dout)[go] = p;
                unsigned short ph_, pl_;
                splitbf(p, ph_, pl_);
                const int off = (q << 7) + ((t << 1) ^ ((q & 7) << 4));
                *(unsigned short*)((char*)Kh + off) = ph_;
                *(unsigned short*)((char*)Kl + off) = pl_;
            }
        }
        __syncthreads();   // P visible to all lanes

        short8 pah[2], pal[2];
        #pragma unroll
        for (int ks = 0; ks < 2; ++ks) {
            const int row = w * 16 + l15;
            const int kb  = (g << 4) + (ks << 6);
            pah[ks] = FRAG(Kh, row, kb);
            pal[ks] = FRAG(Kl, row, kb);
        }
        #pragma unroll
        for (int dsb = 0; dsb < 4; ++dsb) {
            #pragma unroll
            for (int ks = 0; ks < 2; ++ks) {
                const int row = dsb * 16 + l15;
                const int kb  = (g << 4) + (ks << 6);
                short8 vh8 = FRAG(Vh, row, kb);
                short8 vl8 = FRAG(Vl, row, kb);
                cacc[dsb] = MFMA16(pah[ks], vh8, cacc[dsb]);
                cacc[dsb] = MFMA16(pal[ks], vh8, cacc[dsb]);
                cacc[dsb] = MFMA16(pah[ks], vl8, cacc[dsb]);
            }
        }
    }

    const int bb_ = bh / NHEAD, hh_ = bh % NHEAD;
    #pragma unroll
    for (int dsb = 0; dsb < 4; ++dsb) {
        #pragma unroll
        for (int r = 0; r < 4; ++r) {
            const int q = w * 16 + g * 4 + r;
            const int d = dsb * 16 + l15;
            unsigned short hu, lu;
            splitbf(cacc[dsb][r], hu, lu);
            const size_t o = ((size_t)(bb_ * SDIM + r0 + q)) * HDIMT + hh_ * HDHEAD + d;
            ctxh[o] = hu; ctxl[o] = lu;
        }
    }
}

// ---------------- O-projection: split-bf16 MFMA GEMM + residual --------------
__global__ __launch_bounds__(256) void oproj_mfma(
    const unsigned short* __restrict__ ctxh, const unsigned short* __restrict__ ctxl,
    const unsigned short* __restrict__ woh, const unsigned short* __restrict__ wol,
    const void* __restrict__ bo, const void* __restrict__ x,
    float* __restrict__ y, const int* __restrict__ flag)
{
    __shared__ alignas(16) unsigned short Ah[8192], Al[8192];
    __shared__ alignas(16) unsigned short Bh[4096], Bl[4096];

    const int isbf = flag[0];
    const int tid = threadIdx.x;
    const int lane = tid & 63, w = tid >> 6;
    const int l15 = lane & 15, g = lane >> 4;
    const int m0 = blockIdx.x * 128;
    const int h  = blockIdx.y;

    f32x4 acc[2][4];
    #pragma unroll
    for (int i = 0; i < 2; ++i)
        #pragma unroll
        for (int c = 0; c < 4; ++c) acc[i][c] = (f32x4){0.0f, 0.0f, 0.0f, 0.0f};

    for (int k0 = 0; k0 < HDIMT; k0 += 64) {
        __syncthreads();
        #pragma unroll
        for (int p = 0; p < 4; ++p) {
            const int idx = tid + p * 256;
            const int row = idx >> 3, slot = idx & 7;
            const int off = (row << 7) + ((slot << 4) ^ ((row & 7) << 4));
            const size_t s = (size_t)(m0 + row) * HDIMT + k0 + slot * 8;
            *(uint4*)((char*)Ah + off) = *(const uint4*)(ctxh + s);
            *(uint4*)((char*)Al + off) = *(const uint4*)(ctxl + s);
        }
        #pragma unroll
        for (int p = 0; p < 2; ++p) {
            const int idx = tid + p * 256;
            const int row = idx >> 3, slot = idx & 7;
            const int off = (row << 7) + ((slot << 4) ^ ((row & 7) << 4));
            const size_t s = (size_t)(h * 64 + row) * HDIMT + k0 + slot * 8;
            *(uint4*)((char*)Bh + off) = *(const uint4*)(woh + s);
            *(uint4*)((char*)Bl + off) = *(const uint4*)(wol + s);
        }
        __syncthreads();

        #pragma unroll
        for (int ks = 0; ks < 2; ++ks) {
            const int kb = (g << 4) + (ks << 6);
            short8 a8h[2], a8l[2], b8h[4], b8l[4];
            #pragma unroll
            for (int i = 0; i < 2; ++i) {
                const int row = w * 32 + i * 16 + l15;
                a8h[i] = FRAG(Ah, row, kb);
                a8l[i] = FRAG(Al, row, kb);
            }
            #pragma unroll
            for (int c = 0; c < 4; ++c) {
                const int row = c * 16 + l15;
                b8h[c] = FRAG(Bh, row, kb);
                b8l[c] = FRAG(Bl, row, kb);
            }
            #pragma unroll
            for (int i = 0; i < 2; ++i)
                #pragma unroll
                for (int c = 0; c < 4; ++c) {
                    acc[i][c] = MFMA16(a8h[i], b8h[c], acc[i][c]);
                    acc[i][c] = MFMA16(a8l[i], b8h[c], acc[i][c]);
                    acc[i][c] = MFMA16(a8h[i], b8l[c], acc[i][c]);
                }
        }
    }

    float pb[4];
    #pragma unroll
    for (int c = 0; c < 4; ++c) {
        float t = load1f(bo, h * 64 + c * 16 + l15, isbf);
        pb[c] = t + GAMMA * fmaxf(t, 0.0f);
    }

    #pragma unroll
    for (int i = 0; i < 2; ++i)
        #pragma unroll
        for (int c = 0; c < 4; ++c)
            #pragma unroll
            for (int r = 0; r < 4; ++r) {
                const int m = m0 + w * 32 + i * 16 + g * 4 + r;
                const int n = h * 64 + c * 16 + l15;
                const size_t o = (size_t)m * HDIMT + n;
                y[o] = acc[i][c][r] + pb[c] + load1f(x, o, isbf);
            }
}

__global__ __launch_bounds__(256) void ln_kernel(
    const float* __restrict__ y, void* __restrict__ out,
    const int* __restrict__ flag)
{
    __shared__ float red[256];
    const int isbf = flag[0];
    const int m = blockIdx.x;
    const int tid = threadIdx.x;
    const float* yr = y + (size_t)m * HDIMT;

    float v0 = yr[tid], v1 = yr[tid + 256], v2 = yr[tid + 512];

    red[tid] = v0 + v1 + v2;
    __syncthreads();
    for (int s = 128; s > 0; s >>= 1) {
        if (tid < s) red[tid] += red[tid + s];
        __syncthreads();
    }
    const float mean = red[0] * (1.0f / 768.0f);
    __syncthreads();

    const float d0 = v0 - mean, d1 = v1 - mean, d2 = v2 - mean;
    red[tid] = d0 * d0 + d1 * d1 + d2 * d2;
    __syncthreads();
    for (int s = 128; s > 0; s >>= 1) {
        if (tid < s) red[tid] += red[tid + s];
        __syncthreads();
    }
    const float var = red[0] * (1.0f / 767.0f);   // ddof=1
    const float inv = 1.0f / (sqrtf(var) + LNEPS);

    const size_t base = (size_t)m * HDIMT;
    if (isbf) {
        unsigned short* o = (unsigned short*)out;
        o[base + tid]       = f2bf(d0 * inv);
        o[base + tid + 256] = f2bf(d1 * inv);
        o[base + tid + 512] = f2bf(d2 * inv);
    } else {
        float* o = (float*)out;
        o[base + tid]       = d0 * inv;
        o[base + tid + 256] = d1 * inv;
        o[base + tid + 512] = d2 * inv;
    }
}

extern "C" void kernel_launch(void* const* d_in, const int* in_sizes, int n_in,
                              void* d_out, int out_size, void* d_ws, size_t ws_size,
                              hipStream_t stream)
{
    (void)in_sizes; (void)n_in; (void)out_size; (void)ws_size;

    const void* x  = d_in[0];
    const void* Wq = d_in[1];
    const void* bq = d_in[2];
    const void* Wk = d_in[3];
    const void* bk = d_in[4];
    const void* Wv = d_in[5];
    const void* bv = d_in[6];
    const void* Wo = d_in[7];
    const void* bo = d_in[8];

    unsigned short* qh  = (unsigned short*)d_ws;
    unsigned short* ql  = qh  + NEATT;
    unsigned short* kh  = ql  + NEATT;
    unsigned short* kl  = kh  + NEATT;
    unsigned short* vth = kl  + NEATT;
    unsigned short* vtl = vth + NEATT;
    unsigned short* xh  = vtl + NEATT;
    unsigned short* xl  = xh  + NXEL;
    unsigned short* wqh = xl  + NXEL;
    unsigned short* wql = wqh + WNEL;
    unsigned short* wkh = wql + WNEL;
    unsigned short* wkl = wkh + WNEL;
    unsigned short* wvh = wkl + WNEL;
    unsigned short* wvl = wvh + WNEL;
    unsigned short* woh = wvl + WNEL;
    unsigned short* wol = woh + WNEL;
    int* flag = (int*)(wol + WNEL);

    float* y = (float*)qh;                 // q region dead after attn
    unsigned short* ctxh = xh;             // x splits dead after qkv
    unsigned short* ctxl = xl;

    detect_kernel<<<1, 256, 0, stream>>>(x, flag);
    prep_kernel<<<dim3(1536, 5), 256, 0, stream>>>(x, Wq, Wk, Wv, Wo,
                                                   xh, xl, wqh, wql, wkh, wkl,
                                                   wvh, wvl, woh, wol, flag);
    qkv_mfma<<<dim3(32, 12, 3), 256, 0, stream>>>(xh, xl, wqh, wql, wkh, wkl, wvh, wvl,
                                                  bq, bk, bv,
                                                  qh, ql, kh, kl, vth, vtl, flag);
    attn_kernel<<<dim3(32, 24), 256, 0, stream>>>(qh, ql, kh, kl, vth, vtl,
                                                  ctxh, ctxl, d_out, flag);
    oproj_mfma<<<dim3(32, 12), 256, 0, stream>>>(ctxh, ctxl, woh, wol, bo, x, y, flag);
    ln_kernel<<<MTOT, 256, 0, stream>>>(y, d_out, flag);
}